// Round 1
// baseline (649.118 us; speedup 1.0000x reference)
//
#include <hip/hip_runtime.h>

// MoleculeGCN: 2-layer GCN, N=100000 nodes, 128->64->64, E=1600000 edges + self-loops.
// Strategy: build CSR-by-dst once (shared by both layers), then per-layer:
//   GEMM (W in LDS, thread-per-row) -> per-node wave aggregation (lane=feature).

#define GSB 2048  // grid-stride blocks for edge-parallel kernels

// ---------- edge dtype detect (int64 vs int32) ----------
// Examine odd 32-bit words among the first 2*E words. If the array is int64,
// those are the high halves of src values (< 2^17) => all zero. If int32,
// they are random node ids => nonzero almost surely.
__global__ void detect_dtype_kernel(const unsigned* __restrict__ w, long E,
                                    unsigned* __restrict__ flag) {
  unsigned acc = 0;
  long stride = (long)gridDim.x * blockDim.x;
  for (long i = (long)blockIdx.x * blockDim.x + threadIdx.x; i < E; i += stride)
    acc |= w[2 * i + 1];
  if (__any(acc != 0)) {
    if ((threadIdx.x & 63) == 0) atomicOr(flag, 1u);
  }
}

__global__ void convert_edges_kernel(const int* __restrict__ w, int E,
                                     const unsigned* __restrict__ flag,
                                     int* __restrict__ src32, int* __restrict__ dst32) {
  bool is64 = (*flag == 0u);
  int stride = gridDim.x * blockDim.x;
  for (int e = blockIdx.x * blockDim.x + threadIdx.x; e < E; e += stride) {
    if (is64) {
      src32[e] = w[2 * (long)e];            // low word of src[e]
      dst32[e] = w[2 * ((long)E + e)];      // low word of dst[e]
    } else {
      src32[e] = w[e];
      dst32[e] = w[(long)E + e];
    }
  }
}

// ---------- degree / normalization ----------
__global__ void count_deg_kernel(const int* __restrict__ dst, int E, int* __restrict__ cnt) {
  int stride = gridDim.x * blockDim.x;
  for (int e = blockIdx.x * blockDim.x + threadIdx.x; e < E; e += stride)
    atomicAdd(&cnt[dst[e]], 1);
}

__global__ void dinv_kernel(const int* __restrict__ cnt, int n, float* __restrict__ dinv) {
  int i = blockIdx.x * blockDim.x + threadIdx.x;
  if (i < n) dinv[i] = rsqrtf((float)cnt[i] + 1.0f);  // +1 = self loop; deg always > 0
}

// ---------- exclusive scan over cnt[N] ----------
#define SCAN_BS 256
__global__ void scan_block_kernel(const int* __restrict__ cnt, int n, int* __restrict__ bsums) {
  __shared__ int s[SCAN_BS];
  int gid = blockIdx.x * SCAN_BS + threadIdx.x;
  s[threadIdx.x] = (gid < n) ? cnt[gid] : 0;
  __syncthreads();
  for (int st = SCAN_BS / 2; st > 0; st >>= 1) {
    if (threadIdx.x < st) s[threadIdx.x] += s[threadIdx.x + st];
    __syncthreads();
  }
  if (threadIdx.x == 0) bsums[blockIdx.x] = s[0];
}

__global__ void scan_bsums_kernel(int* __restrict__ bsums, int nb) {
  int acc = 0;
  for (int i = 0; i < nb; i++) { int v = bsums[i]; bsums[i] = acc; acc += v; }
}

__global__ void scan_apply_kernel(const int* __restrict__ cnt, int n,
                                  const int* __restrict__ bsums, int* __restrict__ offs) {
  __shared__ int s[SCAN_BS];
  int gid = blockIdx.x * SCAN_BS + threadIdx.x;
  int v = (gid < n) ? cnt[gid] : 0;
  s[threadIdx.x] = v;
  __syncthreads();
  for (int st = 1; st < SCAN_BS; st <<= 1) {
    int t = (threadIdx.x >= st) ? s[threadIdx.x - st] : 0;
    __syncthreads();
    s[threadIdx.x] += t;
    __syncthreads();
  }
  if (gid < n) offs[gid] = bsums[blockIdx.x] + s[threadIdx.x] - v;  // exclusive
}

// ---------- counting-sort scatter: CSR by dst ----------
__global__ void build_csr_kernel(const int* __restrict__ src, const int* __restrict__ dst, int E,
                                 const int* __restrict__ offs, int* __restrict__ fill,
                                 const float* __restrict__ dinv,
                                 int* __restrict__ csrc, float* __restrict__ cnorm) {
  int stride = gridDim.x * blockDim.x;
  for (int e = blockIdx.x * blockDim.x + threadIdx.x; e < E; e += stride) {
    int s = src[e], d = dst[e];
    int pos = offs[d] + atomicAdd(&fill[d], 1);
    csrc[pos] = s;
    cnorm[pos] = dinv[s] * dinv[d];
  }
}

// ---------- GEMM: H[n][64] = X[n][K] @ W[K][64], W staged in LDS ----------
template <int K>
__global__ __launch_bounds__(256) void gemm_kernel(const float* __restrict__ X,
                                                   const float* __restrict__ W,
                                                   float* __restrict__ H, int n) {
  __shared__ float Ws[K * 64];
  for (int i = threadIdx.x; i < K * 64; i += 256) Ws[i] = W[i];
  __syncthreads();
  int row = blockIdx.x * 256 + threadIdx.x;
  if (row >= n) return;
  const float4* xr = (const float4*)(X + (size_t)row * K);
  float acc[64];
#pragma unroll
  for (int c = 0; c < 64; c++) acc[c] = 0.f;
#pragma unroll 4
  for (int k4 = 0; k4 < K / 4; k4++) {
    float4 xv = xr[k4];
#pragma unroll
    for (int kk = 0; kk < 4; kk++) {
      float xs = (kk == 0) ? xv.x : (kk == 1) ? xv.y : (kk == 2) ? xv.z : xv.w;
      const float4* wr = (const float4*)&Ws[(k4 * 4 + kk) * 64];
#pragma unroll
      for (int c4 = 0; c4 < 16; c4++) {
        float4 wv = wr[c4];  // all lanes same address -> LDS broadcast, conflict-free
        acc[c4 * 4 + 0] += xs * wv.x;
        acc[c4 * 4 + 1] += xs * wv.y;
        acc[c4 * 4 + 2] += xs * wv.z;
        acc[c4 * 4 + 3] += xs * wv.w;
      }
    }
  }
  float4* ho = (float4*)(H + (size_t)row * 64);
#pragma unroll
  for (int c4 = 0; c4 < 16; c4++) {
    float4 v;
    v.x = acc[c4 * 4 + 0]; v.y = acc[c4 * 4 + 1];
    v.z = acc[c4 * 4 + 2]; v.w = acc[c4 * 4 + 3];
    ho[c4] = v;
  }
}

// ---------- aggregation: one wave per node, lane = feature ----------
__global__ __launch_bounds__(256) void aggregate_kernel(
    const float* __restrict__ H, const int* __restrict__ offs, const int* __restrict__ cnt,
    const int* __restrict__ csrc, const float* __restrict__ cnorm,
    const float* __restrict__ dinv, const float* __restrict__ bias,
    float* __restrict__ OUT, int n, int relu) {
  int wid = (blockIdx.x * 256 + threadIdx.x) >> 6;
  int lane = threadIdx.x & 63;
  if (wid >= n) return;
  float di = dinv[wid];
  float acc = H[(size_t)wid * 64 + lane] * (di * di);  // self loop
  int i = offs[wid];
  int e = i + cnt[wid];
  for (; i + 1 < e; i += 2) {  // 2-way unroll: two independent gathers in flight
    int sA = csrc[i], sB = csrc[i + 1];
    float nA = cnorm[i], nB = cnorm[i + 1];
    float hA = H[(size_t)sA * 64 + lane];
    float hB = H[(size_t)sB * 64 + lane];
    acc += hA * nA + hB * nB;
  }
  if (i < e) acc += H[(size_t)csrc[i] * 64 + lane] * cnorm[i];
  acc += bias[lane];
  if (relu) acc = fmaxf(acc, 0.f);
  OUT[(size_t)wid * 64 + lane] = acc;
}

extern "C" void kernel_launch(void* const* d_in, const int* in_sizes, int n_in,
                              void* d_out, int out_size, void* d_ws, size_t ws_size,
                              hipStream_t stream) {
  const float* x  = (const float*)d_in[0];
  const int*   ei = (const int*)d_in[1];
  const float* W1 = (const float*)d_in[2];
  const float* b1 = (const float*)d_in[3];
  const float* W2 = (const float*)d_in[4];
  const float* b2 = (const float*)d_in[5];
  float* out = (float*)d_out;

  const int N = in_sizes[0] / 128;
  const int E = in_sizes[1] / 2;  // element count is dtype-independent

  // ---- workspace carve-up (256B aligned) ----
  size_t off = 0;
  char* base = (char*)d_ws;
  auto alloc = [&](size_t bytes) -> void* {
    void* p = base + off;
    off += (bytes + 255) & ~(size_t)255;
    return p;
  };
  int*      cnt  = (int*)alloc((size_t)N * 4);      // } zeroed as one region
  int*      fill = (int*)alloc((size_t)N * 4);      // }
  unsigned* flag = (unsigned*)alloc(256);           // }
  size_t zero_bytes = off;
  int*   offs  = (int*)alloc((size_t)N * 4);
  float* dinv  = (float*)alloc((size_t)N * 4);
  int nb = (N + SCAN_BS - 1) / SCAN_BS;
  int*   bsums = (int*)alloc((size_t)nb * 4);
  int*   src32 = (int*)alloc((size_t)E * 4);
  int*   dst32 = (int*)alloc((size_t)E * 4);
  int*   csrc  = (int*)alloc((size_t)E * 4);
  float* cnorm = (float*)alloc((size_t)E * 4);
  float* h1    = (float*)alloc((size_t)N * 64 * 4);
  float* a1    = (float*)alloc((size_t)N * 64 * 4);
  float* h2    = h1;  // reuse: h1 dead after first aggregation

  hipMemsetAsync(d_ws, 0, zero_bytes, stream);

  // ---- graph prep (shared by both layers) ----
  detect_dtype_kernel<<<GSB, 256, 0, stream>>>((const unsigned*)ei, (long)E, flag);
  convert_edges_kernel<<<GSB, 256, 0, stream>>>(ei, E, flag, src32, dst32);
  count_deg_kernel<<<GSB, 256, 0, stream>>>(dst32, E, cnt);
  dinv_kernel<<<(N + 255) / 256, 256, 0, stream>>>(cnt, N, dinv);
  scan_block_kernel<<<nb, SCAN_BS, 0, stream>>>(cnt, N, bsums);
  scan_bsums_kernel<<<1, 1, 0, stream>>>(bsums, nb);
  scan_apply_kernel<<<nb, SCAN_BS, 0, stream>>>(cnt, N, bsums, offs);
  build_csr_kernel<<<GSB, 256, 0, stream>>>(src32, dst32, E, offs, fill, dinv, csrc, cnorm);

  // ---- layer 1 ----
  gemm_kernel<128><<<(N + 255) / 256, 256, 0, stream>>>(x, W1, h1, N);
  aggregate_kernel<<<(N + 3) / 4, 256, 0, stream>>>(h1, offs, cnt, csrc, cnorm, dinv, b1, a1, N, 1);

  // ---- layer 2 ----
  gemm_kernel<64><<<(N + 255) / 256, 256, 0, stream>>>(a1, W2, h2, N);
  aggregate_kernel<<<(N + 3) / 4, 256, 0, stream>>>(h2, offs, cnt, csrc, cnorm, dinv, b2, out, N, 0);
}

// Round 2
// 531.188 us; speedup vs baseline: 1.2220x; 1.2220x over previous
//
#include <hip/hip_runtime.h>

// MoleculeGCN: 2-layer GCN, N=100000 nodes, 128->64->64, E=1600000 edges + self-loops.
// CSR-by-dst built once (shared by both layers); per-layer GEMM + wave-per-node
// aggregation with coalesced index loads + 8-deep gather pipeline.

#define GSB 2048  // grid-stride blocks for edge-parallel kernels

// ---------- edge dtype detect (int64 vs int32) ----------
__global__ void detect_dtype_kernel(const unsigned* __restrict__ w, long E,
                                    unsigned* __restrict__ flag) {
  unsigned acc = 0;
  long stride = (long)gridDim.x * blockDim.x;
  for (long i = (long)blockIdx.x * blockDim.x + threadIdx.x; i < E; i += stride)
    acc |= w[2 * i + 1];
  if (__any(acc != 0)) {
    if ((threadIdx.x & 63) == 0) atomicOr(flag, 1u);
  }
}

// ---------- convert edges + count in-degree (fused) ----------
__global__ void convert_edges_kernel(const int* __restrict__ w, int E,
                                     const unsigned* __restrict__ flag,
                                     int* __restrict__ src32, int* __restrict__ dst32,
                                     int* __restrict__ cnt) {
  bool is64 = (*flag == 0u);
  int stride = gridDim.x * blockDim.x;
  for (int e = blockIdx.x * blockDim.x + threadIdx.x; e < E; e += stride) {
    int s, d;
    if (is64) {
      s = w[2 * (long)e];            // low word of src[e]
      d = w[2 * ((long)E + e)];      // low word of dst[e]
    } else {
      s = w[e];
      d = w[(long)E + e];
    }
    src32[e] = s;
    dst32[e] = d;
    atomicAdd(&cnt[d], 1);
  }
}

// ---------- exclusive scan over cnt[N] ----------
#define SCAN_BS 256
__global__ void scan_block_kernel(const int* __restrict__ cnt, int n, int* __restrict__ bsums) {
  __shared__ int s[SCAN_BS];
  int gid = blockIdx.x * SCAN_BS + threadIdx.x;
  s[threadIdx.x] = (gid < n) ? cnt[gid] : 0;
  __syncthreads();
  for (int st = SCAN_BS / 2; st > 0; st >>= 1) {
    if (threadIdx.x < st) s[threadIdx.x] += s[threadIdx.x + st];
    __syncthreads();
  }
  if (threadIdx.x == 0) bsums[blockIdx.x] = s[0];
}

// parallel single-block exclusive scan of bsums (chunked Hillis-Steele)
__global__ __launch_bounds__(512) void scan_bsums_kernel(int* __restrict__ bsums, int nb) {
  __shared__ int s[512];
  int carry = 0;
  for (int base = 0; base < nb; base += 512) {
    int g = base + threadIdx.x;
    int v = (g < nb) ? bsums[g] : 0;
    s[threadIdx.x] = v;
    __syncthreads();
    for (int st = 1; st < 512; st <<= 1) {
      int t = (threadIdx.x >= st) ? s[threadIdx.x - st] : 0;
      __syncthreads();
      s[threadIdx.x] += t;
      __syncthreads();
    }
    if (g < nb) bsums[g] = carry + s[threadIdx.x] - v;  // exclusive
    carry += s[511];
    __syncthreads();
  }
}

// offs (exclusive scan of cnt) + dinv (fused)
__global__ void scan_apply_kernel(const int* __restrict__ cnt, int n,
                                  const int* __restrict__ bsums, int* __restrict__ offs,
                                  float* __restrict__ dinv) {
  __shared__ int s[SCAN_BS];
  int gid = blockIdx.x * SCAN_BS + threadIdx.x;
  int v = (gid < n) ? cnt[gid] : 0;
  s[threadIdx.x] = v;
  __syncthreads();
  for (int st = 1; st < SCAN_BS; st <<= 1) {
    int t = (threadIdx.x >= st) ? s[threadIdx.x - st] : 0;
    __syncthreads();
    s[threadIdx.x] += t;
    __syncthreads();
  }
  if (gid < n) {
    offs[gid] = bsums[blockIdx.x] + s[threadIdx.x] - v;  // exclusive
    dinv[gid] = rsqrtf((float)v + 1.0f);                 // +1 = self loop
  }
}

// ---------- counting-sort scatter: CSR by dst ----------
__global__ void build_csr_kernel(const int* __restrict__ src, const int* __restrict__ dst, int E,
                                 const int* __restrict__ offs, int* __restrict__ fill,
                                 const float* __restrict__ dinv,
                                 int* __restrict__ csrc, float* __restrict__ cnorm) {
  int stride = gridDim.x * blockDim.x;
  for (int e = blockIdx.x * blockDim.x + threadIdx.x; e < E; e += stride) {
    int s = src[e], d = dst[e];
    int pos = offs[d] + atomicAdd(&fill[d], 1);
    csrc[pos] = s;
    cnorm[pos] = dinv[s] * dinv[d];
  }
}

// ---------- GEMM: H[n][64] = X[n][K] @ W[K][64], W staged in LDS ----------
template <int K>
__global__ __launch_bounds__(256) void gemm_kernel(const float* __restrict__ X,
                                                   const float* __restrict__ W,
                                                   float* __restrict__ H, int n) {
  __shared__ float Ws[K * 64];
  for (int i = threadIdx.x; i < K * 64; i += 256) Ws[i] = W[i];
  __syncthreads();
  int row = blockIdx.x * 256 + threadIdx.x;
  if (row >= n) return;
  const float4* xr = (const float4*)(X + (size_t)row * K);
  float acc[64];
#pragma unroll
  for (int c = 0; c < 64; c++) acc[c] = 0.f;
#pragma unroll 4
  for (int k4 = 0; k4 < K / 4; k4++) {
    float4 xv = xr[k4];
#pragma unroll
    for (int kk = 0; kk < 4; kk++) {
      float xs = (kk == 0) ? xv.x : (kk == 1) ? xv.y : (kk == 2) ? xv.z : xv.w;
      const float4* wr = (const float4*)&Ws[(k4 * 4 + kk) * 64];
#pragma unroll
      for (int c4 = 0; c4 < 16; c4++) {
        float4 wv = wr[c4];  // same address across lanes -> LDS broadcast
        acc[c4 * 4 + 0] += xs * wv.x;
        acc[c4 * 4 + 1] += xs * wv.y;
        acc[c4 * 4 + 2] += xs * wv.z;
        acc[c4 * 4 + 3] += xs * wv.w;
      }
    }
  }
  float4* ho = (float4*)(H + (size_t)row * 64);
#pragma unroll
  for (int c4 = 0; c4 < 16; c4++) {
    float4 v;
    v.x = acc[c4 * 4 + 0]; v.y = acc[c4 * 4 + 1];
    v.z = acc[c4 * 4 + 2]; v.w = acc[c4 * 4 + 3];
    ho[c4] = v;
  }
}

// ---------- aggregation: one wave per node, lane = feature ----------
// Edge indices/norms loaded COALESCED by the 64 lanes, broadcast via shuffle;
// 8 gathers kept in flight; tail padded with (src=0, norm=0) -> no scalar tail.
__global__ __launch_bounds__(256) void aggregate_kernel(
    const float* __restrict__ H, const int* __restrict__ offs, const int* __restrict__ cnt,
    const int* __restrict__ csrc, const float* __restrict__ cnorm,
    const float* __restrict__ dinv, const float* __restrict__ bias,
    float* __restrict__ OUT, int n, int relu) {
  int wid = (blockIdx.x * 256 + threadIdx.x) >> 6;
  int lane = threadIdx.x & 63;
  if (wid >= n) return;
  float di = dinv[wid];
  float acc = H[(size_t)wid * 64 + lane] * (di * di);  // self loop
  int beg = offs[wid];
  int end = beg + cnt[wid];
  for (int base = beg; base < end; base += 64) {
    int m = min(64, end - base);
    int sl = 0; float nl = 0.f;
    if (lane < m) { sl = csrc[base + lane]; nl = cnorm[base + lane]; }  // coalesced
    int mr = (m + 7) & ~7;  // pad to 8: lanes >= m carry (0, 0.0f) -> no-op terms
    for (int j = 0; j < mr; j += 8) {
      int s0 = __shfl(sl, j + 0), s1 = __shfl(sl, j + 1);
      int s2 = __shfl(sl, j + 2), s3 = __shfl(sl, j + 3);
      int s4 = __shfl(sl, j + 4), s5 = __shfl(sl, j + 5);
      int s6 = __shfl(sl, j + 6), s7 = __shfl(sl, j + 7);
      float w0 = __shfl(nl, j + 0), w1 = __shfl(nl, j + 1);
      float w2 = __shfl(nl, j + 2), w3 = __shfl(nl, j + 3);
      float w4 = __shfl(nl, j + 4), w5 = __shfl(nl, j + 5);
      float w6 = __shfl(nl, j + 6), w7 = __shfl(nl, j + 7);
      float h0 = H[(size_t)s0 * 64 + lane];
      float h1 = H[(size_t)s1 * 64 + lane];
      float h2 = H[(size_t)s2 * 64 + lane];
      float h3 = H[(size_t)s3 * 64 + lane];
      float h4 = H[(size_t)s4 * 64 + lane];
      float h5 = H[(size_t)s5 * 64 + lane];
      float h6 = H[(size_t)s6 * 64 + lane];
      float h7 = H[(size_t)s7 * 64 + lane];
      acc += h0 * w0; acc += h1 * w1; acc += h2 * w2; acc += h3 * w3;
      acc += h4 * w4; acc += h5 * w5; acc += h6 * w6; acc += h7 * w7;
    }
  }
  acc += bias[lane];
  if (relu) acc = fmaxf(acc, 0.f);
  OUT[(size_t)wid * 64 + lane] = acc;
}

extern "C" void kernel_launch(void* const* d_in, const int* in_sizes, int n_in,
                              void* d_out, int out_size, void* d_ws, size_t ws_size,
                              hipStream_t stream) {
  const float* x  = (const float*)d_in[0];
  const int*   ei = (const int*)d_in[1];
  const float* W1 = (const float*)d_in[2];
  const float* b1 = (const float*)d_in[3];
  const float* W2 = (const float*)d_in[4];
  const float* b2 = (const float*)d_in[5];
  float* out = (float*)d_out;

  const int N = in_sizes[0] / 128;
  const int E = in_sizes[1] / 2;

  // ---- workspace carve-up (256B aligned) ----
  size_t off = 0;
  char* base = (char*)d_ws;
  auto alloc = [&](size_t bytes) -> void* {
    void* p = base + off;
    off += (bytes + 255) & ~(size_t)255;
    return p;
  };
  int*      cnt  = (int*)alloc((size_t)N * 4);      // } zeroed as one region
  int*      fill = (int*)alloc((size_t)N * 4);      // }
  unsigned* flag = (unsigned*)alloc(256);           // }
  size_t zero_bytes = off;
  int*   offs  = (int*)alloc((size_t)N * 4);
  float* dinv  = (float*)alloc((size_t)N * 4);
  int nb = (N + SCAN_BS - 1) / SCAN_BS;
  int*   bsums = (int*)alloc((size_t)nb * 4);
  int*   src32 = (int*)alloc((size_t)E * 4);
  int*   dst32 = (int*)alloc((size_t)E * 4);
  int*   csrc  = (int*)alloc((size_t)E * 4);
  float* cnorm = (float*)alloc((size_t)E * 4);
  float* h1    = (float*)alloc((size_t)N * 64 * 4);
  float* a1    = (float*)alloc((size_t)N * 64 * 4);
  float* h2    = h1;  // h1 dead after first aggregation

  hipMemsetAsync(d_ws, 0, zero_bytes, stream);

  // ---- graph prep (shared by both layers) ----
  detect_dtype_kernel<<<GSB, 256, 0, stream>>>((const unsigned*)ei, (long)E, flag);
  convert_edges_kernel<<<GSB, 256, 0, stream>>>(ei, E, flag, src32, dst32, cnt);
  scan_block_kernel<<<nb, SCAN_BS, 0, stream>>>(cnt, N, bsums);
  scan_bsums_kernel<<<1, 512, 0, stream>>>(bsums, nb);
  scan_apply_kernel<<<nb, SCAN_BS, 0, stream>>>(cnt, N, bsums, offs, dinv);
  build_csr_kernel<<<GSB, 256, 0, stream>>>(src32, dst32, E, offs, fill, dinv, csrc, cnorm);

  // ---- layer 1 ----
  gemm_kernel<128><<<(N + 255) / 256, 256, 0, stream>>>(x, W1, h1, N);
  aggregate_kernel<<<(N + 3) / 4, 256, 0, stream>>>(h1, offs, cnt, csrc, cnorm, dinv, b1, a1, N, 1);

  // ---- layer 2 ----
  gemm_kernel<64><<<(N + 255) / 256, 256, 0, stream>>>(a1, W2, h2, N);
  aggregate_kernel<<<(N + 3) / 4, 256, 0, stream>>>(h2, offs, cnt, csrc, cnorm, dinv, b2, out, N, 0);
}

// Round 4
// 443.728 us; speedup vs baseline: 1.4629x; 1.1971x over previous
//
#include <hip/hip_runtime.h>

// MoleculeGCN: 2-layer GCN, N=100000 nodes, 128->64->64, E=1600000 edges + self-loops.
// CSR-by-dst built once (shared by both layers); per-layer GEMM + wave-per-node
// aggregation with coalesced index loads + 16-deep gather pipeline.

#define GSB 2048  // grid-stride blocks for edge-parallel kernels

// ---------- edge dtype detect (int64 vs int32), SAMPLED ----------
// If int64: odd 32-bit words are high halves of node ids (< 2^17) -> all zero.
// If int32: odd words are random node ids -> P(one word==0)=1e-5; 16384 samples
// all-zero under int32 is impossible in practice. One block, ONE plain store —
// the round-2 version did one atomicOr per wave (8192 contended same-line
// atomics ~= 98us, the round-2 top kernel).
__global__ __launch_bounds__(256) void detect_dtype_kernel(const unsigned* __restrict__ w,
                                                           int E, unsigned* __restrict__ flag) {
  __shared__ unsigned sacc;
  if (threadIdx.x == 0) sacc = 0u;
  __syncthreads();
  int ns = min(16384, E);
  unsigned acc = 0;
  for (int i = threadIdx.x; i < ns; i += 256) acc |= w[2 * i + 1];
  if (__any(acc != 0) && (threadIdx.x & 63) == 0) sacc = 1u;  // LDS, not global atomic
  __syncthreads();
  if (threadIdx.x == 0) *flag = sacc;
}

// ---------- convert edges + count in-degree (fused) ----------
__global__ void convert_edges_kernel(const int* __restrict__ w, int E,
                                     const unsigned* __restrict__ flag,
                                     int* __restrict__ src32, int* __restrict__ dst32,
                                     int* __restrict__ cnt) {
  bool is64 = (*flag == 0u);
  int stride = gridDim.x * blockDim.x;
  for (int e = blockIdx.x * blockDim.x + threadIdx.x; e < E; e += stride) {
    int s, d;
    if (is64) {
      s = w[2 * (long)e];            // low word of src[e]
      d = w[2 * ((long)E + e)];      // low word of dst[e]
    } else {
      s = w[e];
      d = w[(long)E + e];
    }
    src32[e] = s;
    dst32[e] = d;
    atomicAdd(&cnt[d], 1);
  }
}

// ---------- exclusive scan over cnt[N] -> offs[N+1] ----------
#define SCAN_BS 256
__global__ void scan_block_kernel(const int* __restrict__ cnt, int n, int* __restrict__ bsums) {
  __shared__ int s[SCAN_BS];
  int gid = blockIdx.x * SCAN_BS + threadIdx.x;
  s[threadIdx.x] = (gid < n) ? cnt[gid] : 0;
  __syncthreads();
  for (int st = SCAN_BS / 2; st > 0; st >>= 1) {
    if (threadIdx.x < st) s[threadIdx.x] += s[threadIdx.x + st];
    __syncthreads();
  }
  if (threadIdx.x == 0) bsums[blockIdx.x] = s[0];
}

// parallel single-block exclusive scan of bsums (chunked Hillis-Steele)
__global__ __launch_bounds__(512) void scan_bsums_kernel(int* __restrict__ bsums, int nb) {
  __shared__ int s[512];
  int carry = 0;
  for (int base = 0; base < nb; base += 512) {
    int g = base + threadIdx.x;
    int v = (g < nb) ? bsums[g] : 0;
    s[threadIdx.x] = v;
    __syncthreads();
    for (int st = 1; st < 512; st <<= 1) {
      int t = (threadIdx.x >= st) ? s[threadIdx.x - st] : 0;
      __syncthreads();
      s[threadIdx.x] += t;
      __syncthreads();
    }
    if (g < nb) bsums[g] = carry + s[threadIdx.x] - v;  // exclusive
    carry += s[511];
    __syncthreads();
  }
}

// offs (exclusive scan of cnt, + sentinel offs[n]=E) + dinv (fused)
__global__ void scan_apply_kernel(const int* __restrict__ cnt, int n,
                                  const int* __restrict__ bsums, int* __restrict__ offs,
                                  float* __restrict__ dinv, int E) {
  __shared__ int s[SCAN_BS];
  int gid = blockIdx.x * SCAN_BS + threadIdx.x;
  int v = (gid < n) ? cnt[gid] : 0;
  s[threadIdx.x] = v;
  __syncthreads();
  for (int st = 1; st < SCAN_BS; st <<= 1) {
    int t = (threadIdx.x >= st) ? s[threadIdx.x - st] : 0;
    __syncthreads();
    s[threadIdx.x] += t;
    __syncthreads();
  }
  if (gid < n) {
    offs[gid] = bsums[blockIdx.x] + s[threadIdx.x] - v;  // exclusive
    dinv[gid] = rsqrtf((float)v + 1.0f);                 // +1 = self loop
    if (gid == n - 1) offs[n] = E;                       // sentinel
  }
}

// ---------- counting-sort scatter: CSR by dst ----------
__global__ void build_csr_kernel(const int* __restrict__ src, const int* __restrict__ dst, int E,
                                 const int* __restrict__ offs, int* __restrict__ fill,
                                 const float* __restrict__ dinv,
                                 int* __restrict__ csrc, float* __restrict__ cnorm) {
  int stride = gridDim.x * blockDim.x;
  for (int e = blockIdx.x * blockDim.x + threadIdx.x; e < E; e += stride) {
    int s = src[e], d = dst[e];
    int pos = offs[d] + atomicAdd(&fill[d], 1);
    csrc[pos] = s;
    cnorm[pos] = dinv[s] * dinv[d];
  }
}

// ---------- GEMM: H[n][64] = X[n][K] @ W[K][64], W staged in LDS ----------
template <int K>
__global__ __launch_bounds__(256) void gemm_kernel(const float* __restrict__ X,
                                                   const float* __restrict__ W,
                                                   float* __restrict__ H, int n) {
  __shared__ float Ws[K * 64];
  for (int i = threadIdx.x; i < K * 64; i += 256) Ws[i] = W[i];
  __syncthreads();
  int row = blockIdx.x * 256 + threadIdx.x;
  if (row >= n) return;
  const float4* xr = (const float4*)(X + (size_t)row * K);
  float acc[64];
#pragma unroll
  for (int c = 0; c < 64; c++) acc[c] = 0.f;
#pragma unroll 4
  for (int k4 = 0; k4 < K / 4; k4++) {
    float4 xv = xr[k4];
#pragma unroll
    for (int kk = 0; kk < 4; kk++) {
      float xs = (kk == 0) ? xv.x : (kk == 1) ? xv.y : (kk == 2) ? xv.z : xv.w;
      const float4* wr = (const float4*)&Ws[(k4 * 4 + kk) * 64];
#pragma unroll
      for (int c4 = 0; c4 < 16; c4++) {
        float4 wv = wr[c4];  // same address across lanes -> LDS broadcast
        acc[c4 * 4 + 0] += xs * wv.x;
        acc[c4 * 4 + 1] += xs * wv.y;
        acc[c4 * 4 + 2] += xs * wv.z;
        acc[c4 * 4 + 3] += xs * wv.w;
      }
    }
  }
  float4* ho = (float4*)(H + (size_t)row * 64);
#pragma unroll
  for (int c4 = 0; c4 < 16; c4++) {
    float4 v;
    v.x = acc[c4 * 4 + 0]; v.y = acc[c4 * 4 + 1];
    v.z = acc[c4 * 4 + 2]; v.w = acc[c4 * 4 + 3];
    ho[c4] = v;
  }
}

// ---------- aggregation: one wave per node, lane = feature ----------
// Edge indices/norms loaded COALESCED by the 64 lanes, broadcast via shuffle;
// 16 gathers kept in flight; tail padded with (src=0, norm=0) -> no scalar tail.
__global__ __launch_bounds__(256) void aggregate_kernel(
    const float* __restrict__ H, const int* __restrict__ offs,
    const int* __restrict__ csrc, const float* __restrict__ cnorm,
    const float* __restrict__ dinv, const float* __restrict__ bias,
    float* __restrict__ OUT, int n, int relu) {
  int wid = (blockIdx.x * 256 + threadIdx.x) >> 6;
  int lane = threadIdx.x & 63;
  if (wid >= n) return;
  float bv = bias[lane];
  float di = dinv[wid];
  int beg = offs[wid];
  int end = offs[wid + 1];
  float acc = H[(size_t)wid * 64 + lane] * (di * di);  // self loop
  for (int base = beg; base < end; base += 64) {
    int m = min(64, end - base);
    int sl = 0; float nl = 0.f;
    if (lane < m) { sl = csrc[base + lane]; nl = cnorm[base + lane]; }  // coalesced
    int mr = (m + 15) & ~15;  // pad to 16: lanes >= m carry (0, 0.0f) -> no-op terms
    for (int j = 0; j < mr; j += 16) {
      int s[16]; float w[16]; float h[16];
#pragma unroll
      for (int t = 0; t < 16; t++) {
        s[t] = __shfl(sl, j + t);
        w[t] = __shfl(nl, j + t);
      }
#pragma unroll
      for (int t = 0; t < 16; t++) h[t] = H[(size_t)s[t] * 64 + lane];  // 16 in flight
#pragma unroll
      for (int t = 0; t < 16; t++) acc += h[t] * w[t];
    }
  }
  acc += bv;
  if (relu) acc = fmaxf(acc, 0.f);
  OUT[(size_t)wid * 64 + lane] = acc;
}

extern "C" void kernel_launch(void* const* d_in, const int* in_sizes, int n_in,
                              void* d_out, int out_size, void* d_ws, size_t ws_size,
                              hipStream_t stream) {
  const float* x  = (const float*)d_in[0];
  const int*   ei = (const int*)d_in[1];
  const float* W1 = (const float*)d_in[2];
  const float* b1 = (const float*)d_in[3];
  const float* W2 = (const float*)d_in[4];
  const float* b2 = (const float*)d_in[5];
  float* out = (float*)d_out;

  const int N = in_sizes[0] / 128;
  const int E = in_sizes[1] / 2;

  // ---- workspace carve-up (256B aligned) ----
  size_t off = 0;
  char* base = (char*)d_ws;
  auto alloc = [&](size_t bytes) -> void* {
    void* p = base + off;
    off += (bytes + 255) & ~(size_t)255;
    return p;
  };
  int*      cnt  = (int*)alloc((size_t)N * 4);      // } zeroed as one region
  int*      fill = (int*)alloc((size_t)N * 4);      // }
  unsigned* flag = (unsigned*)alloc(256);           // }
  size_t zero_bytes = off;
  int*   offs  = (int*)alloc((size_t)(N + 1) * 4);
  float* dinv  = (float*)alloc((size_t)N * 4);
  int nb = (N + SCAN_BS - 1) / SCAN_BS;
  int*   bsums = (int*)alloc((size_t)nb * 4);
  int*   src32 = (int*)alloc((size_t)E * 4);
  int*   dst32 = (int*)alloc((size_t)E * 4);
  int*   csrc  = (int*)alloc((size_t)E * 4);
  float* cnorm = (float*)alloc((size_t)E * 4);
  float* h1    = (float*)alloc((size_t)N * 64 * 4);
  float* a1    = (float*)alloc((size_t)N * 64 * 4);
  float* h2    = h1;  // h1 dead after first aggregation

  hipMemsetAsync(d_ws, 0, zero_bytes, stream);

  // ---- graph prep (shared by both layers) ----
  detect_dtype_kernel<<<1, 256, 0, stream>>>((const unsigned*)ei, E, flag);
  convert_edges_kernel<<<GSB, 256, 0, stream>>>(ei, E, flag, src32, dst32, cnt);
  scan_block_kernel<<<nb, SCAN_BS, 0, stream>>>(cnt, N, bsums);
  scan_bsums_kernel<<<1, 512, 0, stream>>>(bsums, nb);
  scan_apply_kernel<<<nb, SCAN_BS, 0, stream>>>(cnt, N, bsums, offs, dinv, E);
  build_csr_kernel<<<GSB, 256, 0, stream>>>(src32, dst32, E, offs, fill, dinv, csrc, cnorm);

  // ---- layer 1 ----
  gemm_kernel<128><<<(N + 255) / 256, 256, 0, stream>>>(x, W1, h1, N);
  aggregate_kernel<<<(N + 3) / 4, 256, 0, stream>>>(h1, offs, csrc, cnorm, dinv, b1, a1, N, 1);

  // ---- layer 2 ----
  gemm_kernel<64><<<(N + 255) / 256, 256, 0, stream>>>(a1, W2, h2, N);
  aggregate_kernel<<<(N + 3) / 4, 256, 0, stream>>>(h2, offs, csrc, cnorm, dinv, b2, out, N, 0);
}